// Round 1
// 2197.154 us; speedup vs baseline: 1.1814x; 1.1814x over previous
//
#include <hip/hip_runtime.h>
#include <hip/hip_bf16.h>
#include <math.h>

#define B_SZ 8
#define L_SZ 2048
#define D_SZ 1024
#define H_SZ 16
#define DK_SZ 64
#define TOPK 7
#define M_SZ (B_SZ * L_SZ)   // 16384

typedef __attribute__((ext_vector_type(8))) short short8;
typedef __attribute__((ext_vector_type(4))) float float4v;
typedef unsigned short ushort_t;
typedef unsigned int uint_t;

__device__ __forceinline__ ushort_t f2bf(float x) {
    uint_t u = __float_as_uint(x);
    uint_t r = (u + 0x7fffu + ((u >> 16) & 1u)) >> 16;   // RNE
    return (ushort_t)r;
}

// ---------------------------------------------------------------------------
// K0: zero the corr accumulator (re-poisoned to 0xAA before every call)
// ---------------------------------------------------------------------------
__global__ __launch_bounds__(256)
void zero_f32(float* __restrict__ p, int n4) {
    int i = blockIdx.x * 256 + threadIdx.x;
    if (i < n4) ((float4*)p)[i] = make_float4(0.f, 0.f, 0.f, 0.f);
}

// ---------------------------------------------------------------------------
// K1: Y = X @ W^T + bias (X:[M,K], W:[N,K] row-major), fp32 compute.
// BF16OUT: store bf16 (for Q,K feeding the MFMA corr) else fp32.
// ---------------------------------------------------------------------------
#define BM 64
#define BN 64
#define BK 16
#define LDP (BM + 4)

template <bool BF16OUT>
__global__ __launch_bounds__(256)
void sgemm_bias_xt(const float* __restrict__ X, const float* __restrict__ W,
                   const float* __restrict__ bias, void* __restrict__ Yv,
                   int M, int N, int K) {
    __shared__ __align__(16) float As[BK][LDP];
    __shared__ __align__(16) float Bs[BK][LDP];
    const int tid = threadIdx.x;
    const int tx = tid & 15;
    const int ty = tid >> 4;
    const size_t m0 = (size_t)blockIdx.y * BM;
    const size_t n0 = (size_t)blockIdx.x * BN;

    const int lr = tid >> 2;
    const int lk = (tid & 3) * 4;

    float acc[4][4];
#pragma unroll
    for (int i = 0; i < 4; ++i)
#pragma unroll
        for (int j = 0; j < 4; ++j) acc[i][j] = 0.f;

    for (int k0 = 0; k0 < K; k0 += BK) {
        float4 a4 = *(const float4*)(X + (m0 + lr) * K + k0 + lk);
        float4 b4 = *(const float4*)(W + (n0 + lr) * K + k0 + lk);
        As[lk + 0][lr] = a4.x; As[lk + 1][lr] = a4.y;
        As[lk + 2][lr] = a4.z; As[lk + 3][lr] = a4.w;
        Bs[lk + 0][lr] = b4.x; Bs[lk + 1][lr] = b4.y;
        Bs[lk + 2][lr] = b4.z; Bs[lk + 3][lr] = b4.w;
        __syncthreads();
#pragma unroll
        for (int kk = 0; kk < BK; ++kk) {
            float4 av = *(const float4*)&As[kk][ty * 4];
            float4 bv = *(const float4*)&Bs[kk][tx * 4];
            float a[4] = {av.x, av.y, av.z, av.w};
            float b[4] = {bv.x, bv.y, bv.z, bv.w};
#pragma unroll
            for (int i = 0; i < 4; ++i)
#pragma unroll
                for (int j = 0; j < 4; ++j) acc[i][j] += a[i] * b[j];
        }
        __syncthreads();
    }

    const size_t col = n0 + tx * 4;
    float4 bv4 = *(const float4*)(bias + col);
#pragma unroll
    for (int i = 0; i < 4; ++i) {
        const size_t row = m0 + ty * 4 + i;
        float o0 = acc[i][0] + bv4.x, o1 = acc[i][1] + bv4.y;
        float o2 = acc[i][2] + bv4.z, o3 = acc[i][3] + bv4.w;
        if (BF16OUT) {
            ushort4 u; u.x = f2bf(o0); u.y = f2bf(o1); u.z = f2bf(o2); u.w = f2bf(o3);
            *(ushort4*)((ushort_t*)Yv + row * N + col) = u;
        } else {
            *(float4*)((float*)Yv + row * N + col) = make_float4(o0, o1, o2, o3);
        }
    }
}

// ---------------------------------------------------------------------------
// K2: corr via tiled-Gram MFMA.
//   corr[bh, d] += (1/64) * G[t, s]  where d = (t - s) mod L, G = Qh·Khᵀ.
// Tile offset j: t-tile = (s-tile + j) mod 128. For fixed j, accumulate over
// all 128 s-tiles in AGPRs (2 MFMA per s-tile, K=64 split 32+32), then ONE
// scatter of the 16x16 tile into corr[(16j + m - n) & 2047] via atomicAdd.
// grid (128 bh, 4 j-quarters) x 256 thr; wave w owns j = jq*32 + w*8 + [0,8).
//
// v2: rolling 8-slot register window for the Q(A) tiles. Consecutive s0
// iterations share 7/8 Q-tiles, so steady state loads only ONE new Q-tile
// (2x short8) + ONE K-tile (2x short8, prefetched 1 iter ahead) per K-step:
// 4x16B loads feeding 16 MFMAs, all window indices compile-time constant
// (s0 unrolled by 8, slot = (u+jj)&7) so everything stays in registers.
// ---------------------------------------------------------------------------
__global__ __launch_bounds__(256)
void corr_mfma(const ushort_t* __restrict__ Qb, const ushort_t* __restrict__ Kb,
               float* __restrict__ corr) {
    const int wave = threadIdx.x >> 6;
    const int lane = threadIdx.x & 63;
    const int bh = blockIdx.x;
    const int jq = blockIdx.y;
    const int b = bh >> 4, h = bh & 15;
    const int jbase = jq * 32 + wave * 8;
    const int lrow = lane & 15;          // m (A) / n (B) index within tile
    const int kgrp = (lane >> 4) * 8;    // k-offset within a 32-wide chunk

    const size_t slice = (size_t)b * L_SZ * D_SZ + (size_t)h * DK_SZ;
    const ushort_t* Qp = Qb + slice + kgrp;
    const ushort_t* Kp = Kb + slice + kgrp;

    float4v acc[8];
#pragma unroll
    for (int i = 0; i < 8; ++i) acc[i] = (float4v){0.f, 0.f, 0.f, 0.f};

    // Rolling A-window: slot (s0+jj)&7 holds Q-tile ((s0+jj+jbase) & 127).
    // Prologue (s0 = 0): slot i <- tile (jbase + i).
    short8 Wa[8], Wb[8];
#pragma unroll
    for (int i = 0; i < 8; ++i) {
        const size_t tq = (size_t)((((jbase + i) & 127) << 4) + lrow) * D_SZ;
        Wa[i] = *(const short8*)(Qp + tq);
        Wb[i] = *(const short8*)(Qp + tq + 32);
    }
    // K-tile for s0 = 0.
    short8 kb0 = *(const short8*)(Kp + (size_t)lrow * D_SZ);
    short8 kb1 = *(const short8*)(Kp + (size_t)lrow * D_SZ + 32);

    for (int s8 = 0; s8 < 128; s8 += 8) {
#pragma unroll
        for (int u = 0; u < 8; ++u) {
            const int s0 = s8 + u;
            // Prefetch next K-tile (1 iteration ahead; wrap load at the end
            // is harmless, masked index stays in-slice).
            const size_t sn = (size_t)((((s0 + 1) & 127) << 4) + lrow) * D_SZ;
            short8 nk0 = *(const short8*)(Kp + sn);
            short8 nk1 = *(const short8*)(Kp + sn + 32);

            // jj = 0 consumes slot u; refill it right after with the tile
            // needed 8 steps from now (s0+8+jbase), used next at jj=7 of u+1.
            acc[0] = __builtin_amdgcn_mfma_f32_16x16x32_bf16(Wa[u], kb0, acc[0], 0, 0, 0);
            acc[0] = __builtin_amdgcn_mfma_f32_16x16x32_bf16(Wb[u], kb1, acc[0], 0, 0, 0);
            {
                const size_t tq = (size_t)((((s0 + 8 + jbase) & 127) << 4) + lrow) * D_SZ;
                Wa[u] = *(const short8*)(Qp + tq);
                Wb[u] = *(const short8*)(Qp + tq + 32);
            }
#pragma unroll
            for (int jj = 1; jj < 8; ++jj) {
                acc[jj] = __builtin_amdgcn_mfma_f32_16x16x32_bf16(Wa[(u + jj) & 7], kb0, acc[jj], 0, 0, 0);
                acc[jj] = __builtin_amdgcn_mfma_f32_16x16x32_bf16(Wb[(u + jj) & 7], kb1, acc[jj], 0, 0, 0);
            }
            kb0 = nk0; kb1 = nk1;
        }
    }

    // C/D layout (m89-verified): n = lane&15, m = (lane>>4)*4 + reg
    const int n = lane & 15;
    const int mb = (lane >> 4) * 4;
    float* cb = corr + (size_t)bh * L_SZ;
#pragma unroll
    for (int jj = 0; jj < 8; ++jj) {
        const int j16 = (jbase + jj) << 4;
#pragma unroll
        for (int r = 0; r < 4; ++r) {
            const int d = (j16 + mb + r - n) & (L_SZ - 1);
            atomicAdd(cb + d, acc[jj][r] * (1.0f / 64.0f));
        }
    }
}

// ---------------------------------------------------------------------------
// K3: per-(b,h) top-7 (tie -> lowest index) + softmax. One block per bh.
// ---------------------------------------------------------------------------
__global__ __launch_bounds__(256)
void topk_softmax(const float* __restrict__ corr, float* __restrict__ w,
                  int* __restrict__ delays) {
    __shared__ float cv[L_SZ];
    __shared__ float rv[256];
    __shared__ int   ri[256];
    __shared__ float topv[TOPK];
    __shared__ int   topi[TOPK];
    const int bh = blockIdx.x, tid = threadIdx.x;

    for (int i = tid; i < L_SZ; i += 256) cv[i] = corr[(size_t)bh * L_SZ + i];
    __syncthreads();

    for (int it = 0; it < TOPK; ++it) {
        float best = -INFINITY; int bi = 0;
        for (int i = tid; i < L_SZ; i += 256) {
            float x = cv[i];
            if (x > best) { best = x; bi = i; }
        }
        rv[tid] = best; ri[tid] = bi;
        __syncthreads();
        for (int stride = 128; stride > 0; stride >>= 1) {
            if (tid < stride) {
                float ov = rv[tid + stride]; int oi = ri[tid + stride];
                if (ov > rv[tid] || (ov == rv[tid] && oi < ri[tid])) {
                    rv[tid] = ov; ri[tid] = oi;
                }
            }
            __syncthreads();
        }
        if (tid == 0) {
            topv[it] = rv[0]; topi[it] = ri[0];
            cv[ri[0]] = -INFINITY;
        }
        __syncthreads();
    }

    if (tid == 0) {
        float mx = topv[0];
        float e[TOPK], s = 0.f;
#pragma unroll
        for (int i = 0; i < TOPK; ++i) { e[i] = expf(topv[i] - mx); s += e[i]; }
        const float inv = 1.0f / s;
#pragma unroll
        for (int i = 0; i < TOPK; ++i) {
            w[bh * TOPK + i] = e[i] * inv;
            delays[bh * TOPK + i] = topi[i];
        }
    }
}

// ---------------------------------------------------------------------------
// K4: mid[b,t,c] = sum_i w[bh,i] * V[b,(t - delay_i) % L, c]
// ---------------------------------------------------------------------------
__global__ __launch_bounds__(256)
void gather_combine(const float* __restrict__ V, const float* __restrict__ w,
                    const int* __restrict__ delays, float* __restrict__ mid) {
    const size_t g = (size_t)blockIdx.x * 256 + threadIdx.x;
    const int c4 = (int)(g & 255);
    const int t  = (int)((g >> 8) & (L_SZ - 1));
    const int b  = (int)(g >> 19);
    const int h  = c4 >> 4;
    const int bh = b * H_SZ + h;
    const size_t colbase = (size_t)b * L_SZ * D_SZ + (size_t)c4 * 4;

    float4 acc = {0.f, 0.f, 0.f, 0.f};
#pragma unroll
    for (int i = 0; i < TOPK; ++i) {
        const float wi = w[bh * TOPK + i];
        const int   di = delays[bh * TOPK + i];
        const int   ts = (t - di) & (L_SZ - 1);
        float4 v4 = *(const float4*)(V + colbase + (size_t)ts * D_SZ);
        acc.x += wi * v4.x; acc.y += wi * v4.y;
        acc.z += wi * v4.z; acc.w += wi * v4.w;
    }
    *(float4*)(mid + (size_t)b * L_SZ * D_SZ + (size_t)t * D_SZ + c4 * 4) = acc;
}

// ---------------------------------------------------------------------------
extern "C" void kernel_launch(void* const* d_in, const int* in_sizes, int n_in,
                              void* d_out, int out_size, void* d_ws, size_t ws_size,
                              hipStream_t stream) {
    const float* queries = (const float*)d_in[0];
    const float* keys    = (const float*)d_in[1];
    const float* values  = (const float*)d_in[2];
    const float* Wq = (const float*)d_in[3];
    const float* bq = (const float*)d_in[4];
    const float* Wk = (const float*)d_in[5];
    const float* bk = (const float*)d_in[6];
    const float* Wv = (const float*)d_in[7];
    const float* bv = (const float*)d_in[8];
    const float* Wo = (const float*)d_in[9];
    const float* bo = (const float*)d_in[10];

    const size_t NE = (size_t)M_SZ * D_SZ;          // 16.78M elements
    ushort_t* Qb16 = (ushort_t*)d_ws;               // 33.5 MB
    ushort_t* Kb16 = Qb16 + NE;                     // 33.5 MB
    float* Vb   = (float*)(Kb16 + NE);              // 64 MB
    float* corr = Vb + NE;                          // 1 MB (B*H*L fp32)
    float* wbuf = corr + (size_t)B_SZ * H_SZ * L_SZ;
    int*   dbuf = (int*)(wbuf + B_SZ * H_SZ * TOPK);
    float* mid  = (float*)d_ws;  // aliases Qb16+Kb16 (67MB >= 64MB, dead after corr)

    dim3 ggemm(D_SZ / BN, M_SZ / BM);   // (16, 256)

    zero_f32<<<(B_SZ * H_SZ * L_SZ / 4 + 255) / 256, 256, 0, stream>>>(
        corr, B_SZ * H_SZ * L_SZ / 4);

    sgemm_bias_xt<true><<<ggemm, 256, 0, stream>>>(queries, Wq, bq, Qb16, M_SZ, D_SZ, D_SZ);
    sgemm_bias_xt<true><<<ggemm, 256, 0, stream>>>(keys,    Wk, bk, Kb16, M_SZ, D_SZ, D_SZ);
    sgemm_bias_xt<false><<<ggemm, 256, 0, stream>>>(values, Wv, bv, Vb,  M_SZ, D_SZ, D_SZ);

    corr_mfma<<<dim3(B_SZ * H_SZ, 4), 256, 0, stream>>>(Qb16, Kb16, corr);

    topk_softmax<<<B_SZ * H_SZ, 256, 0, stream>>>(corr, wbuf, dbuf);

    gather_combine<<<(M_SZ * 256) / 256, 256, 0, stream>>>(Vb, wbuf, dbuf, mid);

    sgemm_bias_xt<false><<<ggemm, 256, 0, stream>>>(mid, Wo, bo, (float*)d_out, M_SZ, D_SZ, D_SZ);
}

// Round 2
// 871.030 us; speedup vs baseline: 2.9802x; 2.5225x over previous
//
#include <hip/hip_runtime.h>
#include <hip/hip_bf16.h>
#include <math.h>

#define B_SZ 8
#define L_SZ 2048
#define D_SZ 1024
#define H_SZ 16
#define DK_SZ 64
#define TOPK 7
#define M_SZ (B_SZ * L_SZ)   // 16384

typedef __attribute__((ext_vector_type(8))) short short8;
typedef __attribute__((ext_vector_type(4))) float float4v;
typedef unsigned short ushort_t;
typedef unsigned int uint_t;

__device__ __forceinline__ ushort_t f2bf(float x) {
    uint_t u = __float_as_uint(x);
    uint_t r = (u + 0x7fffu + ((u >> 16) & 1u)) >> 16;   // RNE
    return (ushort_t)r;
}

// Truncation split: x ~= hi + lo with |err| <= 2^-16 |x|.
// hi = top16(x); lo = top16(x - hi). ~4 VALU/elem, no sw-RNE chains.
__device__ __forceinline__ void split8(float4 x, float4 y, short8& hi, short8& lo) {
    float f[8] = {x.x, x.y, x.z, x.w, y.x, y.y, y.z, y.w};
#pragma unroll
    for (int i = 0; i < 8; ++i) {
        uint_t b = __float_as_uint(f[i]);
        hi[i] = (short)(b >> 16);
        float r = f[i] - __uint_as_float(b & 0xffff0000u);
        lo[i] = (short)(__float_as_uint(r) >> 16);
    }
}

// ---------------------------------------------------------------------------
// K0: zero the corr accumulator (re-poisoned to 0xAA before every call)
// ---------------------------------------------------------------------------
__global__ __launch_bounds__(256)
void zero_f32(float* __restrict__ p, int n4) {
    int i = blockIdx.x * 256 + threadIdx.x;
    if (i < n4) ((float4*)p)[i] = make_float4(0.f, 0.f, 0.f, 0.f);
}

// ---------------------------------------------------------------------------
// K0b: split a fp32 array into hi/lo bf16 arrays (used for the W matrices,
// 4 MB each -> ~3 us; avoids 128x redundant in-GEMM conversion of B tiles).
// ---------------------------------------------------------------------------
__global__ __launch_bounds__(256)
void split_fp32(const float* __restrict__ X, ushort_t* __restrict__ hi,
                ushort_t* __restrict__ lo, int n8) {
    int i = blockIdx.x * 256 + threadIdx.x;
    if (i >= n8) return;
    float4 a = ((const float4*)X)[2 * i];
    float4 b = ((const float4*)X)[2 * i + 1];
    short8 h, l;
    split8(a, b, h, l);
    *(short8*)(hi + (size_t)i * 8) = h;
    *(short8*)(lo + (size_t)i * 8) = l;
}

// ---------------------------------------------------------------------------
// K1: Y = X @ W^T + bias via split-bf16 MFMA (3 passes: hh + hl + lh).
//   X:[M,K] fp32 (split in-kernel at staging), W pre-split hi/lo [N,K] bf16.
//   Tile 128x128, BK=32, 4 waves (2x2), wave tile 64x64 (4x4 16x16 frags).
//   LDS granule-major layout [k/8][row][8]: conflict-free (<=2-way) for both
//   ds_read_b128 fragment reads and ds_write_b128 staging writes.
//   48 MFMA / 16 ds_read_b128 / wave / K-step; next tile's global loads
//   issued before the MFMA section (latency hidden under matrix pipe).
// ---------------------------------------------------------------------------
template <bool BF16OUT>
__global__ __launch_bounds__(256)
void gemm_split_mfma(const float* __restrict__ X, const ushort_t* __restrict__ Whi,
                     const ushort_t* __restrict__ Wlo, const float* __restrict__ bias,
                     void* __restrict__ Yv, int M, int N, int K) {
    __shared__ __align__(16) short Ah[4][128][8];
    __shared__ __align__(16) short Al[4][128][8];
    __shared__ __align__(16) short Bh[4][128][8];
    __shared__ __align__(16) short Bl[4][128][8];

    const int tid = threadIdx.x;
    const int lane = tid & 63;
    const int wave = tid >> 6;
    const int wm = wave >> 1, wn = wave & 1;
    const size_t m0 = (size_t)blockIdx.y * 128;
    const size_t n0 = (size_t)blockIdx.x * 128;

    const int srow = tid >> 1;           // staging row 0..127
    const int g0 = (tid & 1) * 2;        // first k-granule this thread writes
    const int skseg = (tid & 1) * 16;    // k offset 0 or 16

    const float*    Xp  = X   + (m0 + srow) * K + skseg;
    const ushort_t* Whp = Whi + (n0 + srow) * K + skseg;
    const ushort_t* Wlp = Wlo + (n0 + srow) * K + skseg;

    const int fr = lane & 15;            // frag row/col
    const int fg = lane >> 4;            // frag k-granule (k = fg*8..+8)

    // prologue: tile 0 into regs
    float4 ax0 = *(const float4*)(Xp + 0);
    float4 ax1 = *(const float4*)(Xp + 4);
    float4 ax2 = *(const float4*)(Xp + 8);
    float4 ax3 = *(const float4*)(Xp + 12);
    short8 bh0 = *(const short8*)(Whp + 0);
    short8 bh1 = *(const short8*)(Whp + 8);
    short8 bl0 = *(const short8*)(Wlp + 0);
    short8 bl1 = *(const short8*)(Wlp + 8);

    float4v acc[4][4];
#pragma unroll
    for (int i = 0; i < 4; ++i)
#pragma unroll
        for (int j = 0; j < 4; ++j) acc[i][j] = (float4v){0.f, 0.f, 0.f, 0.f};

    for (int k0 = 0; k0 < K; k0 += 32) {
        __syncthreads();                 // previous tile's reads done
        short8 h, l;
        split8(ax0, ax1, h, l);
        *(short8*)&Ah[g0][srow][0] = h;      *(short8*)&Al[g0][srow][0] = l;
        split8(ax2, ax3, h, l);
        *(short8*)&Ah[g0 + 1][srow][0] = h;  *(short8*)&Al[g0 + 1][srow][0] = l;
        *(short8*)&Bh[g0][srow][0] = bh0;    *(short8*)&Bh[g0 + 1][srow][0] = bh1;
        *(short8*)&Bl[g0][srow][0] = bl0;    *(short8*)&Bl[g0 + 1][srow][0] = bl1;
        __syncthreads();                 // tile visible

        if (k0 + 32 < K) {               // issue next tile's loads early (T14)
            ax0 = *(const float4*)(Xp + k0 + 32);
            ax1 = *(const float4*)(Xp + k0 + 36);
            ax2 = *(const float4*)(Xp + k0 + 40);
            ax3 = *(const float4*)(Xp + k0 + 44);
            bh0 = *(const short8*)(Whp + k0 + 32);
            bh1 = *(const short8*)(Whp + k0 + 40);
            bl0 = *(const short8*)(Wlp + k0 + 32);
            bl1 = *(const short8*)(Wlp + k0 + 40);
        }

        short8 afh[4], afl[4], bfh[4], bfl[4];
#pragma unroll
        for (int i = 0; i < 4; ++i) {
            const int r = wm * 64 + i * 16 + fr;
            afh[i] = *(const short8*)&Ah[fg][r][0];
            afl[i] = *(const short8*)&Al[fg][r][0];
        }
#pragma unroll
        for (int j = 0; j < 4; ++j) {
            const int r = wn * 64 + j * 16 + fr;
            bfh[j] = *(const short8*)&Bh[fg][r][0];
            bfl[j] = *(const short8*)&Bl[fg][r][0];
        }
#pragma unroll
        for (int i = 0; i < 4; ++i)
#pragma unroll
            for (int j = 0; j < 4; ++j) {
                acc[i][j] = __builtin_amdgcn_mfma_f32_16x16x32_bf16(afh[i], bfh[j], acc[i][j], 0, 0, 0);
                acc[i][j] = __builtin_amdgcn_mfma_f32_16x16x32_bf16(afh[i], bfl[j], acc[i][j], 0, 0, 0);
                acc[i][j] = __builtin_amdgcn_mfma_f32_16x16x32_bf16(afl[i], bfh[j], acc[i][j], 0, 0, 0);
            }
    }

    // epilogue: C/D layout (m89-verified): col = lane&15, row = (lane>>4)*4 + r
    const int en = fr;
    const int emb = (lane >> 4) * 4;
#pragma unroll
    for (int j = 0; j < 4; ++j) {
        const size_t col = n0 + wn * 64 + j * 16 + en;
        const float bv = bias[col];
#pragma unroll
        for (int i = 0; i < 4; ++i) {
#pragma unroll
            for (int r = 0; r < 4; ++r) {
                const size_t row = m0 + wm * 64 + i * 16 + emb + r;
                const float o = acc[i][j][r] + bv;
                if (BF16OUT) ((ushort_t*)Yv)[row * N + col] = f2bf(o);
                else         ((float*)Yv)[row * N + col] = o;
            }
        }
    }
}

// ---------------------------------------------------------------------------
// K2: corr via tiled-Gram MFMA (rolling 8-slot register window, v2 — see R0).
// ---------------------------------------------------------------------------
__global__ __launch_bounds__(256)
void corr_mfma(const ushort_t* __restrict__ Qb, const ushort_t* __restrict__ Kb,
               float* __restrict__ corr) {
    const int wave = threadIdx.x >> 6;
    const int lane = threadIdx.x & 63;
    const int bh = blockIdx.x;
    const int jq = blockIdx.y;
    const int b = bh >> 4, h = bh & 15;
    const int jbase = jq * 32 + wave * 8;
    const int lrow = lane & 15;
    const int kgrp = (lane >> 4) * 8;

    const size_t slice = (size_t)b * L_SZ * D_SZ + (size_t)h * DK_SZ;
    const ushort_t* Qp = Qb + slice + kgrp;
    const ushort_t* Kp = Kb + slice + kgrp;

    float4v acc[8];
#pragma unroll
    for (int i = 0; i < 8; ++i) acc[i] = (float4v){0.f, 0.f, 0.f, 0.f};

    short8 Wa[8], Wb[8];
#pragma unroll
    for (int i = 0; i < 8; ++i) {
        const size_t tq = (size_t)((((jbase + i) & 127) << 4) + lrow) * D_SZ;
        Wa[i] = *(const short8*)(Qp + tq);
        Wb[i] = *(const short8*)(Qp + tq + 32);
    }
    short8 kb0 = *(const short8*)(Kp + (size_t)lrow * D_SZ);
    short8 kb1 = *(const short8*)(Kp + (size_t)lrow * D_SZ + 32);

    for (int s8 = 0; s8 < 128; s8 += 8) {
#pragma unroll
        for (int u = 0; u < 8; ++u) {
            const int s0 = s8 + u;
            const size_t sn = (size_t)((((s0 + 1) & 127) << 4) + lrow) * D_SZ;
            short8 nk0 = *(const short8*)(Kp + sn);
            short8 nk1 = *(const short8*)(Kp + sn + 32);

            acc[0] = __builtin_amdgcn_mfma_f32_16x16x32_bf16(Wa[u], kb0, acc[0], 0, 0, 0);
            acc[0] = __builtin_amdgcn_mfma_f32_16x16x32_bf16(Wb[u], kb1, acc[0], 0, 0, 0);
            {
                const size_t tq = (size_t)((((s0 + 8 + jbase) & 127) << 4) + lrow) * D_SZ;
                Wa[u] = *(const short8*)(Qp + tq);
                Wb[u] = *(const short8*)(Qp + tq + 32);
            }
#pragma unroll
            for (int jj = 1; jj < 8; ++jj) {
                acc[jj] = __builtin_amdgcn_mfma_f32_16x16x32_bf16(Wa[(u + jj) & 7], kb0, acc[jj], 0, 0, 0);
                acc[jj] = __builtin_amdgcn_mfma_f32_16x16x32_bf16(Wb[(u + jj) & 7], kb1, acc[jj], 0, 0, 0);
            }
            kb0 = nk0; kb1 = nk1;
        }
    }

    const int n = lane & 15;
    const int mb = (lane >> 4) * 4;
    float* cb = corr + (size_t)bh * L_SZ;
#pragma unroll
    for (int jj = 0; jj < 8; ++jj) {
        const int j16 = (jbase + jj) << 4;
#pragma unroll
        for (int r = 0; r < 4; ++r) {
            const int d = (j16 + mb + r - n) & (L_SZ - 1);
            atomicAdd(cb + d, acc[jj][r] * (1.0f / 64.0f));
        }
    }
}

// ---------------------------------------------------------------------------
// K3: per-(b,h) top-7 (tie -> lowest index) + softmax. One block per bh.
// ---------------------------------------------------------------------------
__global__ __launch_bounds__(256)
void topk_softmax(const float* __restrict__ corr, float* __restrict__ w,
                  int* __restrict__ delays) {
    __shared__ float cv[L_SZ];
    __shared__ float rv[256];
    __shared__ int   ri[256];
    __shared__ float topv[TOPK];
    __shared__ int   topi[TOPK];
    const int bh = blockIdx.x, tid = threadIdx.x;

    for (int i = tid; i < L_SZ; i += 256) cv[i] = corr[(size_t)bh * L_SZ + i];
    __syncthreads();

    for (int it = 0; it < TOPK; ++it) {
        float best = -INFINITY; int bi = 0;
        for (int i = tid; i < L_SZ; i += 256) {
            float x = cv[i];
            if (x > best) { best = x; bi = i; }
        }
        rv[tid] = best; ri[tid] = bi;
        __syncthreads();
        for (int stride = 128; stride > 0; stride >>= 1) {
            if (tid < stride) {
                float ov = rv[tid + stride]; int oi = ri[tid + stride];
                if (ov > rv[tid] || (ov == rv[tid] && oi < ri[tid])) {
                    rv[tid] = ov; ri[tid] = oi;
                }
            }
            __syncthreads();
        }
        if (tid == 0) {
            topv[it] = rv[0]; topi[it] = ri[0];
            cv[ri[0]] = -INFINITY;
        }
        __syncthreads();
    }

    if (tid == 0) {
        float mx = topv[0];
        float e[TOPK], s = 0.f;
#pragma unroll
        for (int i = 0; i < TOPK; ++i) { e[i] = expf(topv[i] - mx); s += e[i]; }
        const float inv = 1.0f / s;
#pragma unroll
        for (int i = 0; i < TOPK; ++i) {
            w[bh * TOPK + i] = e[i] * inv;
            delays[bh * TOPK + i] = topi[i];
        }
    }
}

// ---------------------------------------------------------------------------
// K4: mid[b,t,c] = sum_i w[bh,i] * V[b,(t - delay_i) % L, c]
// ---------------------------------------------------------------------------
__global__ __launch_bounds__(256)
void gather_combine(const float* __restrict__ V, const float* __restrict__ w,
                    const int* __restrict__ delays, float* __restrict__ mid) {
    const size_t g = (size_t)blockIdx.x * 256 + threadIdx.x;
    const int c4 = (int)(g & 255);
    const int t  = (int)((g >> 8) & (L_SZ - 1));
    const int b  = (int)(g >> 19);
    const int h  = c4 >> 4;
    const int bh = b * H_SZ + h;
    const size_t colbase = (size_t)b * L_SZ * D_SZ + (size_t)c4 * 4;

    float4 acc = {0.f, 0.f, 0.f, 0.f};
#pragma unroll
    for (int i = 0; i < TOPK; ++i) {
        const float wi = w[bh * TOPK + i];
        const int   di = delays[bh * TOPK + i];
        const int   ts = (t - di) & (L_SZ - 1);
        float4 v4 = *(const float4*)(V + colbase + (size_t)ts * D_SZ);
        acc.x += wi * v4.x; acc.y += wi * v4.y;
        acc.z += wi * v4.z; acc.w += wi * v4.w;
    }
    *(float4*)(mid + (size_t)b * L_SZ * D_SZ + (size_t)t * D_SZ + c4 * 4) = acc;
}

// ---------------------------------------------------------------------------
extern "C" void kernel_launch(void* const* d_in, const int* in_sizes, int n_in,
                              void* d_out, int out_size, void* d_ws, size_t ws_size,
                              hipStream_t stream) {
    const float* queries = (const float*)d_in[0];
    const float* keys    = (const float*)d_in[1];
    const float* values  = (const float*)d_in[2];
    const float* Wq = (const float*)d_in[3];
    const float* bq = (const float*)d_in[4];
    const float* Wk = (const float*)d_in[5];
    const float* bk = (const float*)d_in[6];
    const float* Wv = (const float*)d_in[7];
    const float* bv = (const float*)d_in[8];
    const float* Wo = (const float*)d_in[9];
    const float* bo = (const float*)d_in[10];

    const size_t NE = (size_t)M_SZ * D_SZ;          // 16.78M elements
    ushort_t* Qb16 = (ushort_t*)d_ws;               // 33.5 MB
    ushort_t* Kb16 = Qb16 + NE;                     // 33.5 MB
    float* Vb   = (float*)(Kb16 + NE);              // 67.1 MB
    float* corr = Vb + NE;                          // 1 MB (B*H*L fp32)
    float* wbuf = corr + (size_t)B_SZ * H_SZ * L_SZ;
    int*   dbuf = (int*)(wbuf + B_SZ * H_SZ * TOPK);
    ushort_t* WH = (ushort_t*)(dbuf + B_SZ * H_SZ * TOPK);  // 2 MB (reused)
    ushort_t* WL = WH + (size_t)D_SZ * D_SZ;                // 2 MB (reused)
    float* mid  = (float*)d_ws;  // aliases Qb16+Kb16 (67MB, dead after corr)

    dim3 ggemm(D_SZ / 128, M_SZ / 128);   // (8, 128)
    const int wn8 = D_SZ * D_SZ / 8;      // 131072

    split_fp32<<<(wn8 + 255) / 256, 256, 0, stream>>>(Wq, WH, WL, wn8);
    gemm_split_mfma<true><<<ggemm, 256, 0, stream>>>(queries, WH, WL, bq, Qb16, M_SZ, D_SZ, D_SZ);
    split_fp32<<<(wn8 + 255) / 256, 256, 0, stream>>>(Wk, WH, WL, wn8);
    gemm_split_mfma<true><<<ggemm, 256, 0, stream>>>(keys, WH, WL, bk, Kb16, M_SZ, D_SZ, D_SZ);
    split_fp32<<<(wn8 + 255) / 256, 256, 0, stream>>>(Wv, WH, WL, wn8);
    gemm_split_mfma<false><<<ggemm, 256, 0, stream>>>(values, WH, WL, bv, Vb, M_SZ, D_SZ, D_SZ);

    zero_f32<<<(B_SZ * H_SZ * L_SZ / 4 + 255) / 256, 256, 0, stream>>>(
        corr, B_SZ * H_SZ * L_SZ / 4);

    corr_mfma<<<dim3(B_SZ * H_SZ, 4), 256, 0, stream>>>(Qb16, Kb16, corr);

    topk_softmax<<<B_SZ * H_SZ, 256, 0, stream>>>(corr, wbuf, dbuf);

    gather_combine<<<(M_SZ * 256) / 256, 256, 0, stream>>>(Vb, wbuf, dbuf, mid);

    split_fp32<<<(wn8 + 255) / 256, 256, 0, stream>>>(Wo, WH, WL, wn8);
    gemm_split_mfma<false><<<ggemm, 256, 0, stream>>>(mid, WH, WL, bo, (float*)d_out, M_SZ, D_SZ, D_SZ);
}

// Round 3
// 816.677 us; speedup vs baseline: 3.1785x; 1.0666x over previous
//
#include <hip/hip_runtime.h>
#include <hip/hip_bf16.h>
#include <math.h>

#define B_SZ 8
#define L_SZ 2048
#define D_SZ 1024
#define H_SZ 16
#define DK_SZ 64
#define TOPK 7
#define M_SZ (B_SZ * L_SZ)   // 16384

typedef __attribute__((ext_vector_type(8))) short short8;
typedef __attribute__((ext_vector_type(4))) float float4v;
typedef unsigned short ushort_t;
typedef unsigned int uint_t;

__device__ __forceinline__ ushort_t f2bf(float x) {
    uint_t u = __float_as_uint(x);
    uint_t r = (u + 0x7fffu + ((u >> 16) & 1u)) >> 16;   // RNE
    return (ushort_t)r;
}

// Truncation split: x ~= hi + lo with |err| <= 2^-16 |x|.
__device__ __forceinline__ void split8(float4 x, float4 y, short8& hi, short8& lo) {
    float f[8] = {x.x, x.y, x.z, x.w, y.x, y.y, y.z, y.w};
#pragma unroll
    for (int i = 0; i < 8; ++i) {
        uint_t b = __float_as_uint(f[i]);
        hi[i] = (short)(b >> 16);
        float r = f[i] - __uint_as_float(b & 0xffff0000u);
        lo[i] = (short)(__float_as_uint(r) >> 16);
    }
}

// async global->LDS, 16B per lane. LDS dest must be wave-uniform base.
__device__ __forceinline__ void gl_lds16(const ushort_t* g, ushort_t* l) {
    __builtin_amdgcn_global_load_lds(
        (const __attribute__((address_space(1))) unsigned int*)g,
        (__attribute__((address_space(3))) unsigned int*)l, 16, 0, 0);
}

// ---------------------------------------------------------------------------
// K0: zero the corr accumulator (re-poisoned to 0xAA before every call)
// ---------------------------------------------------------------------------
__global__ __launch_bounds__(256)
void zero_f32(float* __restrict__ p, int n4) {
    int i = blockIdx.x * 256 + threadIdx.x;
    if (i < n4) ((float4*)p)[i] = make_float4(0.f, 0.f, 0.f, 0.f);
}

// ---------------------------------------------------------------------------
// K0b: split a fp32 array into hi/lo bf16 arrays (for the W matrices).
// ---------------------------------------------------------------------------
__global__ __launch_bounds__(256)
void split_fp32(const float* __restrict__ X, ushort_t* __restrict__ hi,
                ushort_t* __restrict__ lo, int n8) {
    int i = blockIdx.x * 256 + threadIdx.x;
    if (i >= n8) return;
    float4 a = ((const float4*)X)[2 * i];
    float4 b = ((const float4*)X)[2 * i + 1];
    short8 h, l;
    split8(a, b, h, l);
    *(short8*)(hi + (size_t)i * 8) = h;
    *(short8*)(lo + (size_t)i * 8) = l;
}

// ---------------------------------------------------------------------------
// K1: Y = X @ W^T + bias via split-bf16 MFMA (3 passes: hh + hl + lh).
// (unchanged from R2 — near its 2-barrier-structure ceiling)
// ---------------------------------------------------------------------------
template <bool BF16OUT>
__global__ __launch_bounds__(256)
void gemm_split_mfma(const float* __restrict__ X, const ushort_t* __restrict__ Whi,
                     const ushort_t* __restrict__ Wlo, const float* __restrict__ bias,
                     void* __restrict__ Yv, int M, int N, int K) {
    __shared__ __align__(16) short Ah[4][128][8];
    __shared__ __align__(16) short Al[4][128][8];
    __shared__ __align__(16) short Bh[4][128][8];
    __shared__ __align__(16) short Bl[4][128][8];

    const int tid = threadIdx.x;
    const int lane = tid & 63;
    const int wave = tid >> 6;
    const int wm = wave >> 1, wn = wave & 1;
    const size_t m0 = (size_t)blockIdx.y * 128;
    const size_t n0 = (size_t)blockIdx.x * 128;

    const int srow = tid >> 1;
    const int g0 = (tid & 1) * 2;
    const int skseg = (tid & 1) * 16;

    const float*    Xp  = X   + (m0 + srow) * K + skseg;
    const ushort_t* Whp = Whi + (n0 + srow) * K + skseg;
    const ushort_t* Wlp = Wlo + (n0 + srow) * K + skseg;

    const int fr = lane & 15;
    const int fg = lane >> 4;

    float4 ax0 = *(const float4*)(Xp + 0);
    float4 ax1 = *(const float4*)(Xp + 4);
    float4 ax2 = *(const float4*)(Xp + 8);
    float4 ax3 = *(const float4*)(Xp + 12);
    short8 bh0 = *(const short8*)(Whp + 0);
    short8 bh1 = *(const short8*)(Whp + 8);
    short8 bl0 = *(const short8*)(Wlp + 0);
    short8 bl1 = *(const short8*)(Wlp + 8);

    float4v acc[4][4];
#pragma unroll
    for (int i = 0; i < 4; ++i)
#pragma unroll
        for (int j = 0; j < 4; ++j) acc[i][j] = (float4v){0.f, 0.f, 0.f, 0.f};

    for (int k0 = 0; k0 < K; k0 += 32) {
        __syncthreads();
        short8 h, l;
        split8(ax0, ax1, h, l);
        *(short8*)&Ah[g0][srow][0] = h;      *(short8*)&Al[g0][srow][0] = l;
        split8(ax2, ax3, h, l);
        *(short8*)&Ah[g0 + 1][srow][0] = h;  *(short8*)&Al[g0 + 1][srow][0] = l;
        *(short8*)&Bh[g0][srow][0] = bh0;    *(short8*)&Bh[g0 + 1][srow][0] = bh1;
        *(short8*)&Bl[g0][srow][0] = bl0;    *(short8*)&Bl[g0 + 1][srow][0] = bl1;
        __syncthreads();

        if (k0 + 32 < K) {
            ax0 = *(const float4*)(Xp + k0 + 32);
            ax1 = *(const float4*)(Xp + k0 + 36);
            ax2 = *(const float4*)(Xp + k0 + 40);
            ax3 = *(const float4*)(Xp + k0 + 44);
            bh0 = *(const short8*)(Whp + k0 + 32);
            bh1 = *(const short8*)(Whp + k0 + 40);
            bl0 = *(const short8*)(Wlp + k0 + 32);
            bl1 = *(const short8*)(Wlp + k0 + 40);
        }

        short8 afh[4], afl[4], bfh[4], bfl[4];
#pragma unroll
        for (int i = 0; i < 4; ++i) {
            const int r = wm * 64 + i * 16 + fr;
            afh[i] = *(const short8*)&Ah[fg][r][0];
            afl[i] = *(const short8*)&Al[fg][r][0];
        }
#pragma unroll
        for (int j = 0; j < 4; ++j) {
            const int r = wn * 64 + j * 16 + fr;
            bfh[j] = *(const short8*)&Bh[fg][r][0];
            bfl[j] = *(const short8*)&Bl[fg][r][0];
        }
#pragma unroll
        for (int i = 0; i < 4; ++i)
#pragma unroll
            for (int j = 0; j < 4; ++j) {
                acc[i][j] = __builtin_amdgcn_mfma_f32_16x16x32_bf16(afh[i], bfh[j], acc[i][j], 0, 0, 0);
                acc[i][j] = __builtin_amdgcn_mfma_f32_16x16x32_bf16(afh[i], bfl[j], acc[i][j], 0, 0, 0);
                acc[i][j] = __builtin_amdgcn_mfma_f32_16x16x32_bf16(afl[i], bfh[j], acc[i][j], 0, 0, 0);
            }
    }

    const int en = fr;
    const int emb = (lane >> 4) * 4;
#pragma unroll
    for (int j = 0; j < 4; ++j) {
        const size_t col = n0 + wn * 64 + j * 16 + en;
        const float bv = bias[col];
#pragma unroll
        for (int i = 0; i < 4; ++i) {
#pragma unroll
            for (int r = 0; r < 4; ++r) {
                const size_t row = m0 + wm * 64 + i * 16 + emb + r;
                const float o = acc[i][j][r] + bv;
                if (BF16OUT) ((ushort_t*)Yv)[row * N + col] = f2bf(o);
                else         ((float*)Yv)[row * N + col] = o;
            }
        }
    }
}

// ---------------------------------------------------------------------------
// K2 v3: corr via tiled-Gram MFMA, LDS-shared tile rings.
//   Previously each of the 4 waves loaded its own Q-refill + K-tile from
//   global (16KB/block/step -> 1.07GB total, cache-BW-bound at ~6TB/s).
//   Now: stage 1 Q-tile + 1 K-tile per step into LDS rings (4KB/block/step,
//   one global_load_lds(16B)/thread), refill register windows from LDS.
//   Q ring: 28 slots (56KB) covers waves' union span [s0+8, s0+32] plus
//   2-deep prefetch; K ring: 4 slots (8KB). Total 64KB -> 2 blocks/CU.
//   Sync: raw s_barrier + counted vmcnt(2) (T4) — stages stay in flight
//   across barriers. Ring math gives >=2-barrier separation between the
//   last read of a slot and its overwrite (verified per-slot below).
//   LDS swizzle: source-side XOR (chunk ^= row&7), read-side same XOR
//   (rule #21 involution) -> ds_read_b128 spreads 8 lanes/bank-quad.
// ---------------------------------------------------------------------------
__global__ __launch_bounds__(256)
void corr_mfma(const ushort_t* __restrict__ Qb, const ushort_t* __restrict__ Kb,
               float* __restrict__ corr) {
    __shared__ __align__(16) ushort_t Qlds[28 * 1024];  // 28 tiles x 2KB
    __shared__ __align__(16) ushort_t Klds[4 * 1024];   // 4 tiles x 2KB

    const int tid  = threadIdx.x;
    const int wave = tid >> 6;
    const int lane = tid & 63;
    const int bh = blockIdx.x;
    const int jq = blockIdx.y;
    const int b = bh >> 4, h = bh & 15;
    const int b0 = jq * 32;                  // block's base j-tile offset
    const int jbase = b0 + wave * 8;         // this wave's base j
    const int rr = lane & 15;                // fragment row
    const int cq = lane >> 4;                // wanted 16B chunk (0..3)
    const int s7 = rr & 7;

    const size_t slice = (size_t)b * L_SZ * D_SZ + (size_t)h * DK_SZ;
    const ushort_t* Qs = Qb + slice;         // head-sliced, row stride D_SZ
    const ushort_t* Ks = Kb + slice;
    const ushort_t* Qp = Qs + cq * 8;        // for the global reg-prologue

    // staging thread mapping: threads 0..127 -> Q tile, 128..255 -> K tile
    const int st  = tid & 127;
    const int sr  = st >> 3;                 // tile row 0..15
    const int sc  = (st & 7) ^ (sr & 7);     // pre-swizzled source chunk
    const int whalf = (wave & 1) * 512;      // LDS half-tile base (shorts)

    // fragment-read offsets within a tile (shorts), swizzled
    const int roff0 = rr * 64 + ((cq ^ s7) * 8);
    const int roff1 = roff0 ^ 32;            // chunk +4 (k+32 elems)

    float4v acc[8];
#pragma unroll
    for (int i = 0; i < 8; ++i) acc[i] = (float4v){0.f, 0.f, 0.f, 0.f};

    // ---- prologue staging: Q tiles b0+8..b0+33 -> slots 0..25; K tiles 0..2
    if (wave < 2) {
        for (int i = 0; i < 26; ++i) {
            const int qt = (b0 + 8 + i) & 127;
            gl_lds16(Qs + (size_t)(qt * 16 + sr) * 1024 + sc * 8,
                     &Qlds[i * 1024 + whalf]);
        }
    } else {
        for (int i = 0; i < 3; ++i) {
            gl_lds16(Ks + (size_t)(i * 16 + sr) * 1024 + sc * 8,
                     &Klds[i * 1024 + whalf]);
        }
    }

    // ---- register-window prologue from GLOBAL (tiles b0+8w+[0,8))
    short8 Wa[8], Wb[8];
#pragma unroll
    for (int i = 0; i < 8; ++i) {
        const size_t tq = (size_t)((((jbase + i) & 127) << 4) + rr) * D_SZ;
        Wa[i] = *(const short8*)(Qp + tq);
        Wb[i] = *(const short8*)(Qp + tq + 32);
    }

    asm volatile("s_waitcnt vmcnt(0)" ::: "memory");
    __builtin_amdgcn_s_barrier();
    asm volatile("" ::: "memory");

    // kb for s-tile 0 from LDS slot 0
    short8 kb0 = *(const short8*)&Klds[roff0];
    short8 kb1 = *(const short8*)&Klds[roff1];

    int qsr = wave * 8;   // LDS slot of this wave's refill tile (b0+8+8w+s0)
    int qsw = 26;         // LDS slot being staged (tile b0+34+s0)

    for (int s8 = 0; s8 < 128; s8 += 8) {
#pragma unroll
        for (int u = 0; u < 8; ++u) {
            const int s0 = s8 + u;
            // ---- stage phase: exactly 1 gload_lds per thread
            if (wave < 2) {
                const int qt = (b0 + 34 + s0) & 127;
                gl_lds16(Qs + (size_t)(qt * 16 + sr) * 1024 + sc * 8,
                         &Qlds[qsw * 1024 + whalf]);
            } else {
                const int kt = (s0 + 3) & 127;
                gl_lds16(Ks + (size_t)(kt * 16 + sr) * 1024 + sc * 8,
                         &Klds[((s0 + 3) & 3) * 1024 + whalf]);
            }
            asm volatile("s_waitcnt vmcnt(2)" ::: "memory");
            __builtin_amdgcn_s_barrier();
            asm volatile("" ::: "memory");

            // ---- compute phase
            const int kslot = ((s0 + 1) & 3) * 1024;   // K tile s0+1 (next)
            short8 nk0 = *(const short8*)&Klds[kslot + roff0];
            short8 nk1 = *(const short8*)&Klds[kslot + roff1];

            acc[0] = __builtin_amdgcn_mfma_f32_16x16x32_bf16(Wa[u], kb0, acc[0], 0, 0, 0);
            acc[0] = __builtin_amdgcn_mfma_f32_16x16x32_bf16(Wb[u], kb1, acc[0], 0, 0, 0);
            {   // refill consumed slot u with tile b0+8+8w+s0 from LDS
                const int qbse = qsr * 1024;
                Wa[u] = *(const short8*)&Qlds[qbse + roff0];
                Wb[u] = *(const short8*)&Qlds[qbse + roff1];
            }
#pragma unroll
            for (int jj = 1; jj < 8; ++jj) {
                acc[jj] = __builtin_amdgcn_mfma_f32_16x16x32_bf16(Wa[(u + jj) & 7], kb0, acc[jj], 0, 0, 0);
                acc[jj] = __builtin_amdgcn_mfma_f32_16x16x32_bf16(Wb[(u + jj) & 7], kb1, acc[jj], 0, 0, 0);
            }
            kb0 = nk0; kb1 = nk1;
            qsr = (qsr + 1 == 28) ? 0 : qsr + 1;
            qsw = (qsw + 1 == 28) ? 0 : qsw + 1;
        }
    }

    // C/D layout (m89-verified): n = lane&15, m = (lane>>4)*4 + reg
    const int n = lane & 15;
    const int mb = (lane >> 4) * 4;
    float* cb = corr + (size_t)bh * L_SZ;
#pragma unroll
    for (int jj = 0; jj < 8; ++jj) {
        const int j16 = (jbase + jj) << 4;
#pragma unroll
        for (int r = 0; r < 4; ++r) {
            const int d = (j16 + mb + r - n) & (L_SZ - 1);
            atomicAdd(cb + d, acc[jj][r] * (1.0f / 64.0f));
        }
    }
}

// ---------------------------------------------------------------------------
// K3: per-(b,h) top-7 (tie -> lowest index) + softmax. One block per bh.
// ---------------------------------------------------------------------------
__global__ __launch_bounds__(256)
void topk_softmax(const float* __restrict__ corr, float* __restrict__ w,
                  int* __restrict__ delays) {
    __shared__ float cv[L_SZ];
    __shared__ float rv[256];
    __shared__ int   ri[256];
    __shared__ float topv[TOPK];
    __shared__ int   topi[TOPK];
    const int bh = blockIdx.x, tid = threadIdx.x;

    for (int i = tid; i < L_SZ; i += 256) cv[i] = corr[(size_t)bh * L_SZ + i];
    __syncthreads();

    for (int it = 0; it < TOPK; ++it) {
        float best = -INFINITY; int bi = 0;
        for (int i = tid; i < L_SZ; i += 256) {
            float x = cv[i];
            if (x > best) { best = x; bi = i; }
        }
        rv[tid] = best; ri[tid] = bi;
        __syncthreads();
        for (int stride = 128; stride > 0; stride >>= 1) {
            if (tid < stride) {
                float ov = rv[tid + stride]; int oi = ri[tid + stride];
                if (ov > rv[tid] || (ov == rv[tid] && oi < ri[tid])) {
                    rv[tid] = ov; ri[tid] = oi;
                }
            }
            __syncthreads();
        }
        if (tid == 0) {
            topv[it] = rv[0]; topi[it] = ri[0];
            cv[ri[0]] = -INFINITY;
        }
        __syncthreads();
    }

    if (tid == 0) {
        float mx = topv[0];
        float e[TOPK], s = 0.f;
#pragma unroll
        for (int i = 0; i < TOPK; ++i) { e[i] = expf(topv[i] - mx); s += e[i]; }
        const float inv = 1.0f / s;
#pragma unroll
        for (int i = 0; i < TOPK; ++i) {
            w[bh * TOPK + i] = e[i] * inv;
            delays[bh * TOPK + i] = topi[i];
        }
    }
}

// ---------------------------------------------------------------------------
// K4: mid[b,t,c] = sum_i w[bh,i] * V[b,(t - delay_i) % L, c]
// ---------------------------------------------------------------------------
__global__ __launch_bounds__(256)
void gather_combine(const float* __restrict__ V, const float* __restrict__ w,
                    const int* __restrict__ delays, float* __restrict__ mid) {
    const size_t g = (size_t)blockIdx.x * 256 + threadIdx.x;
    const int c4 = (int)(g & 255);
    const int t  = (int)((g >> 8) & (L_SZ - 1));
    const int b  = (int)(g >> 19);
    const int h  = c4 >> 4;
    const int bh = b * H_SZ + h;
    const size_t colbase = (size_t)b * L_SZ * D_SZ + (size_t)c4 * 4;

    float4 acc = {0.f, 0.f, 0.f, 0.f};
#pragma unroll
    for (int i = 0; i < TOPK; ++i) {
        const float wi = w[bh * TOPK + i];
        const int   di = delays[bh * TOPK + i];
        const int   ts = (t - di) & (L_SZ - 1);
        float4 v4 = *(const float4*)(V + colbase + (size_t)ts * D_SZ);
        acc.x += wi * v4.x; acc.y += wi * v4.y;
        acc.z += wi * v4.z; acc.w += wi * v4.w;
    }
    *(float4*)(mid + (size_t)b * L_SZ * D_SZ + (size_t)t * D_SZ + c4 * 4) = acc;
}

// ---------------------------------------------------------------------------
extern "C" void kernel_launch(void* const* d_in, const int* in_sizes, int n_in,
                              void* d_out, int out_size, void* d_ws, size_t ws_size,
                              hipStream_t stream) {
    const float* queries = (const float*)d_in[0];
    const float* keys    = (const float*)d_in[1];
    const float* values  = (const float*)d_in[2];
    const float* Wq = (const float*)d_in[3];
    const float* bq = (const float*)d_in[4];
    const float* Wk = (const float*)d_in[5];
    const float* bk = (const float*)d_in[6];
    const float* Wv = (const float*)d_in[7];
    const float* bv = (const float*)d_in[8];
    const float* Wo = (const float*)d_in[9];
    const float* bo = (const float*)d_in[10];

    const size_t NE = (size_t)M_SZ * D_SZ;          // 16.78M elements
    ushort_t* Qb16 = (ushort_t*)d_ws;               // 33.5 MB
    ushort_t* Kb16 = Qb16 + NE;                     // 33.5 MB
    float* Vb   = (float*)(Kb16 + NE);              // 67.1 MB
    float* corr = Vb + NE;                          // 1 MB (B*H*L fp32)
    float* wbuf = corr + (size_t)B_SZ * H_SZ * L_SZ;
    int*   dbuf = (int*)(wbuf + B_SZ * H_SZ * TOPK);
    ushort_t* WH = (ushort_t*)(dbuf + B_SZ * H_SZ * TOPK);  // 2 MB (reused)
    ushort_t* WL = WH + (size_t)D_SZ * D_SZ;                // 2 MB (reused)
    float* mid  = (float*)d_ws;  // aliases Qb16+Kb16 (67MB, dead after corr)

    dim3 ggemm(D_SZ / 128, M_SZ / 128);   // (8, 128)
    const int wn8 = D_SZ * D_SZ / 8;      // 131072

    split_fp32<<<(wn8 + 255) / 256, 256, 0, stream>>>(Wq, WH, WL, wn8);
    gemm_split_mfma<true><<<ggemm, 256, 0, stream>>>(queries, WH, WL, bq, Qb16, M_SZ, D_SZ, D_SZ);
    split_fp32<<<(wn8 + 255) / 256, 256, 0, stream>>>(Wk, WH, WL, wn8);
    gemm_split_mfma<true><<<ggemm, 256, 0, stream>>>(keys, WH, WL, bk, Kb16, M_SZ, D_SZ, D_SZ);
    split_fp32<<<(wn8 + 255) / 256, 256, 0, stream>>>(Wv, WH, WL, wn8);
    gemm_split_mfma<false><<<ggemm, 256, 0, stream>>>(values, WH, WL, bv, Vb, M_SZ, D_SZ, D_SZ);

    zero_f32<<<(B_SZ * H_SZ * L_SZ / 4 + 255) / 256, 256, 0, stream>>>(
        corr, B_SZ * H_SZ * L_SZ / 4);

    corr_mfma<<<dim3(B_SZ * H_SZ, 4), 256, 0, stream>>>(Qb16, Kb16, corr);

    topk_softmax<<<B_SZ * H_SZ, 256, 0, stream>>>(corr, wbuf, dbuf);

    gather_combine<<<(M_SZ * 256) / 256, 256, 0, stream>>>(Vb, wbuf, dbuf, mid);

    split_fp32<<<(wn8 + 255) / 256, 256, 0, stream>>>(Wo, WH, WL, wn8);
    gemm_split_mfma<false><<<ggemm, 256, 0, stream>>>(mid, WH, WL, bo, (float*)d_out, M_SZ, D_SZ, D_SZ);
}

// Round 4
// 795.815 us; speedup vs baseline: 3.2618x; 1.0262x over previous
//
#include <hip/hip_runtime.h>
#include <hip/hip_bf16.h>
#include <math.h>

#define B_SZ 8
#define L_SZ 2048
#define D_SZ 1024
#define H_SZ 16
#define DK_SZ 64
#define TOPK 7
#define M_SZ (B_SZ * L_SZ)   // 16384

typedef __attribute__((ext_vector_type(8))) short short8;
typedef __attribute__((ext_vector_type(4))) float float4v;
typedef unsigned short ushort_t;
typedef unsigned int uint_t;

__device__ __forceinline__ ushort_t f2bf(float x) {
    uint_t u = __float_as_uint(x);
    uint_t r = (u + 0x7fffu + ((u >> 16) & 1u)) >> 16;   // RNE
    return (ushort_t)r;
}

// Truncation split: x ~= hi + lo with |err| <= 2^-16 |x|.
__device__ __forceinline__ void split8(float4 x, float4 y, short8& hi, short8& lo) {
    float f[8] = {x.x, x.y, x.z, x.w, y.x, y.y, y.z, y.w};
#pragma unroll
    for (int i = 0; i < 8; ++i) {
        uint_t b = __float_as_uint(f[i]);
        hi[i] = (short)(b >> 16);
        float r = f[i] - __uint_as_float(b & 0xffff0000u);
        lo[i] = (short)(__float_as_uint(r) >> 16);
    }
}

// async global->LDS, 16B per lane. LDS dest must be wave-uniform base.
__device__ __forceinline__ void gl_lds16(const ushort_t* g, ushort_t* l) {
    __builtin_amdgcn_global_load_lds(
        (const __attribute__((address_space(1))) unsigned int*)g,
        (__attribute__((address_space(3))) unsigned int*)l, 16, 0, 0);
}

// ---------------------------------------------------------------------------
// K0: zero the corr accumulator (re-poisoned to 0xAA before every call)
// ---------------------------------------------------------------------------
__global__ __launch_bounds__(256)
void zero_f32(float* __restrict__ p, int n4) {
    int i = blockIdx.x * 256 + threadIdx.x;
    if (i < n4) ((float4*)p)[i] = make_float4(0.f, 0.f, 0.f, 0.f);
}

// ---------------------------------------------------------------------------
// K0b: split a fp32 array into hi/lo bf16 arrays (for the W matrices).
// ---------------------------------------------------------------------------
__global__ __launch_bounds__(256)
void split_fp32(const float* __restrict__ X, ushort_t* __restrict__ hi,
                ushort_t* __restrict__ lo, int n8) {
    int i = blockIdx.x * 256 + threadIdx.x;
    if (i >= n8) return;
    float4 a = ((const float4*)X)[2 * i];
    float4 b = ((const float4*)X)[2 * i + 1];
    short8 h, l;
    split8(a, b, h, l);
    *(short8*)(hi + (size_t)i * 8) = h;
    *(short8*)(lo + (size_t)i * 8) = l;
}

// ---------------------------------------------------------------------------
// K1: Y = X @ W^T + bias via split-bf16 MFMA (3 passes: hh + hl + lh).
//   v2: XCD-chunked block swizzle (T1). Grid (8,128) dispatches x-fastest,
//   so the 8 n-blocks sharing an A row-band landed on 8 DIFFERENT XCD L2s
//   -> A re-fetched from HBM (FETCH 266MB vs 71MB compulsory). Remap
//   swz = (flat&7)*128 + flat>>3 (bijective, 1024%8==0), decoded n-fastest:
//   each XCD owns a contiguous 16-block m-band and the 8 n-siblings of an
//   A panel run back-to-back on the SAME XCD -> A re-reads become L2 hits,
//   which also shortens the vmcnt-drain stall at each barrier (L2 ~200cy
//   vs HBM ~900cy, MFMA section ~700cy of cover).
// ---------------------------------------------------------------------------
template <bool BF16OUT>
__global__ __launch_bounds__(256)
void gemm_split_mfma(const float* __restrict__ X, const ushort_t* __restrict__ Whi,
                     const ushort_t* __restrict__ Wlo, const float* __restrict__ bias,
                     void* __restrict__ Yv, int M, int N, int K) {
    __shared__ __align__(16) short Ah[4][128][8];
    __shared__ __align__(16) short Al[4][128][8];
    __shared__ __align__(16) short Bh[4][128][8];
    __shared__ __align__(16) short Bl[4][128][8];

    const int tid = threadIdx.x;
    const int lane = tid & 63;
    const int wave = tid >> 6;
    const int wm = wave >> 1, wn = wave & 1;

    // T1 XCD-chunked swizzle (nwg = gridDim.x * gridDim.y, x = n-dim)
    const int flat = blockIdx.y * gridDim.x + blockIdx.x;
    const int cpx  = (gridDim.x * gridDim.y) >> 3;          // blocks per XCD
    const int swz  = (flat & 7) * cpx + (flat >> 3);
    const int bx   = swz % gridDim.x;                       // n-fastest
    const int by   = swz / gridDim.x;
    const size_t m0 = (size_t)by * 128;
    const size_t n0 = (size_t)bx * 128;

    const int srow = tid >> 1;
    const int g0 = (tid & 1) * 2;
    const int skseg = (tid & 1) * 16;

    const float*    Xp  = X   + (m0 + srow) * K + skseg;
    const ushort_t* Whp = Whi + (n0 + srow) * K + skseg;
    const ushort_t* Wlp = Wlo + (n0 + srow) * K + skseg;

    const int fr = lane & 15;
    const int fg = lane >> 4;

    float4 ax0 = *(const float4*)(Xp + 0);
    float4 ax1 = *(const float4*)(Xp + 4);
    float4 ax2 = *(const float4*)(Xp + 8);
    float4 ax3 = *(const float4*)(Xp + 12);
    short8 bh0 = *(const short8*)(Whp + 0);
    short8 bh1 = *(const short8*)(Whp + 8);
    short8 bl0 = *(const short8*)(Wlp + 0);
    short8 bl1 = *(const short8*)(Wlp + 8);

    float4v acc[4][4];
#pragma unroll
    for (int i = 0; i < 4; ++i)
#pragma unroll
        for (int j = 0; j < 4; ++j) acc[i][j] = (float4v){0.f, 0.f, 0.f, 0.f};

    for (int k0 = 0; k0 < K; k0 += 32) {
        __syncthreads();
        short8 h, l;
        split8(ax0, ax1, h, l);
        *(short8*)&Ah[g0][srow][0] = h;      *(short8*)&Al[g0][srow][0] = l;
        split8(ax2, ax3, h, l);
        *(short8*)&Ah[g0 + 1][srow][0] = h;  *(short8*)&Al[g0 + 1][srow][0] = l;
        *(short8*)&Bh[g0][srow][0] = bh0;    *(short8*)&Bh[g0 + 1][srow][0] = bh1;
        *(short8*)&Bl[g0][srow][0] = bl0;    *(short8*)&Bl[g0 + 1][srow][0] = bl1;
        __syncthreads();

        if (k0 + 32 < K) {
            ax0 = *(const float4*)(Xp + k0 + 32);
            ax1 = *(const float4*)(Xp + k0 + 36);
            ax2 = *(const float4*)(Xp + k0 + 40);
            ax3 = *(const float4*)(Xp + k0 + 44);
            bh0 = *(const short8*)(Whp + k0 + 32);
            bh1 = *(const short8*)(Whp + k0 + 40);
            bl0 = *(const short8*)(Wlp + k0 + 32);
            bl1 = *(const short8*)(Wlp + k0 + 40);
        }

        short8 afh[4], afl[4], bfh[4], bfl[4];
#pragma unroll
        for (int i = 0; i < 4; ++i) {
            const int r = wm * 64 + i * 16 + fr;
            afh[i] = *(const short8*)&Ah[fg][r][0];
            afl[i] = *(const short8*)&Al[fg][r][0];
        }
#pragma unroll
        for (int j = 0; j < 4; ++j) {
            const int r = wn * 64 + j * 16 + fr;
            bfh[j] = *(const short8*)&Bh[fg][r][0];
            bfl[j] = *(const short8*)&Bl[fg][r][0];
        }
#pragma unroll
        for (int i = 0; i < 4; ++i)
#pragma unroll
            for (int j = 0; j < 4; ++j) {
                acc[i][j] = __builtin_amdgcn_mfma_f32_16x16x32_bf16(afh[i], bfh[j], acc[i][j], 0, 0, 0);
                acc[i][j] = __builtin_amdgcn_mfma_f32_16x16x32_bf16(afh[i], bfl[j], acc[i][j], 0, 0, 0);
                acc[i][j] = __builtin_amdgcn_mfma_f32_16x16x32_bf16(afl[i], bfh[j], acc[i][j], 0, 0, 0);
            }
    }

    const int en = fr;
    const int emb = (lane >> 4) * 4;
#pragma unroll
    for (int j = 0; j < 4; ++j) {
        const size_t col = n0 + wn * 64 + j * 16 + en;
        const float bv = bias[col];
#pragma unroll
        for (int i = 0; i < 4; ++i) {
#pragma unroll
            for (int r = 0; r < 4; ++r) {
                const size_t row = m0 + wm * 64 + i * 16 + emb + r;
                const float o = acc[i][j][r] + bv;
                if (BF16OUT) ((ushort_t*)Yv)[row * N + col] = f2bf(o);
                else         ((float*)Yv)[row * N + col] = o;
            }
        }
    }
}

// ---------------------------------------------------------------------------
// K2 v3: corr via tiled-Gram MFMA, LDS-shared tile rings (see R2 notes).
// (unchanged — dropped off top-5 after the ring rewrite)
// ---------------------------------------------------------------------------
__global__ __launch_bounds__(256)
void corr_mfma(const ushort_t* __restrict__ Qb, const ushort_t* __restrict__ Kb,
               float* __restrict__ corr) {
    __shared__ __align__(16) ushort_t Qlds[28 * 1024];  // 28 tiles x 2KB
    __shared__ __align__(16) ushort_t Klds[4 * 1024];   // 4 tiles x 2KB

    const int tid  = threadIdx.x;
    const int wave = tid >> 6;
    const int lane = tid & 63;
    const int bh = blockIdx.x;
    const int jq = blockIdx.y;
    const int b = bh >> 4, h = bh & 15;
    const int b0 = jq * 32;
    const int jbase = b0 + wave * 8;
    const int rr = lane & 15;
    const int cq = lane >> 4;
    const int s7 = rr & 7;

    const size_t slice = (size_t)b * L_SZ * D_SZ + (size_t)h * DK_SZ;
    const ushort_t* Qs = Qb + slice;
    const ushort_t* Ks = Kb + slice;
    const ushort_t* Qp = Qs + cq * 8;

    const int st  = tid & 127;
    const int sr  = st >> 3;
    const int sc  = (st & 7) ^ (sr & 7);
    const int whalf = (wave & 1) * 512;

    const int roff0 = rr * 64 + ((cq ^ s7) * 8);
    const int roff1 = roff0 ^ 32;

    float4v acc[8];
#pragma unroll
    for (int i = 0; i < 8; ++i) acc[i] = (float4v){0.f, 0.f, 0.f, 0.f};

    if (wave < 2) {
        for (int i = 0; i < 26; ++i) {
            const int qt = (b0 + 8 + i) & 127;
            gl_lds16(Qs + (size_t)(qt * 16 + sr) * 1024 + sc * 8,
                     &Qlds[i * 1024 + whalf]);
        }
    } else {
        for (int i = 0; i < 3; ++i) {
            gl_lds16(Ks + (size_t)(i * 16 + sr) * 1024 + sc * 8,
                     &Klds[i * 1024 + whalf]);
        }
    }

    short8 Wa[8], Wb[8];
#pragma unroll
    for (int i = 0; i < 8; ++i) {
        const size_t tq = (size_t)((((jbase + i) & 127) << 4) + rr) * D_SZ;
        Wa[i] = *(const short8*)(Qp + tq);
        Wb[i] = *(const short8*)(Qp + tq + 32);
    }

    asm volatile("s_waitcnt vmcnt(0)" ::: "memory");
    __builtin_amdgcn_s_barrier();
    asm volatile("" ::: "memory");

    short8 kb0 = *(const short8*)&Klds[roff0];
    short8 kb1 = *(const short8*)&Klds[roff1];

    int qsr = wave * 8;
    int qsw = 26;

    for (int s8 = 0; s8 < 128; s8 += 8) {
#pragma unroll
        for (int u = 0; u < 8; ++u) {
            const int s0 = s8 + u;
            if (wave < 2) {
                const int qt = (b0 + 34 + s0) & 127;
                gl_lds16(Qs + (size_t)(qt * 16 + sr) * 1024 + sc * 8,
                         &Qlds[qsw * 1024 + whalf]);
            } else {
                const int kt = (s0 + 3) & 127;
                gl_lds16(Ks + (size_t)(kt * 16 + sr) * 1024 + sc * 8,
                         &Klds[((s0 + 3) & 3) * 1024 + whalf]);
            }
            asm volatile("s_waitcnt vmcnt(2)" ::: "memory");
            __builtin_amdgcn_s_barrier();
            asm volatile("" ::: "memory");

            const int kslot = ((s0 + 1) & 3) * 1024;
            short8 nk0 = *(const short8*)&Klds[kslot + roff0];
            short8 nk1 = *(const short8*)&Klds[kslot + roff1];

            acc[0] = __builtin_amdgcn_mfma_f32_16x16x32_bf16(Wa[u], kb0, acc[0], 0, 0, 0);
            acc[0] = __builtin_amdgcn_mfma_f32_16x16x32_bf16(Wb[u], kb1, acc[0], 0, 0, 0);
            {
                const int qbse = qsr * 1024;
                Wa[u] = *(const short8*)&Qlds[qbse + roff0];
                Wb[u] = *(const short8*)&Qlds[qbse + roff1];
            }
#pragma unroll
            for (int jj = 1; jj < 8; ++jj) {
                acc[jj] = __builtin_amdgcn_mfma_f32_16x16x32_bf16(Wa[(u + jj) & 7], kb0, acc[jj], 0, 0, 0);
                acc[jj] = __builtin_amdgcn_mfma_f32_16x16x32_bf16(Wb[(u + jj) & 7], kb1, acc[jj], 0, 0, 0);
            }
            kb0 = nk0; kb1 = nk1;
            qsr = (qsr + 1 == 28) ? 0 : qsr + 1;
            qsw = (qsw + 1 == 28) ? 0 : qsw + 1;
        }
    }

    const int n = lane & 15;
    const int mb = (lane >> 4) * 4;
    float* cb = corr + (size_t)bh * L_SZ;
#pragma unroll
    for (int jj = 0; jj < 8; ++jj) {
        const int j16 = (jbase + jj) << 4;
#pragma unroll
        for (int r = 0; r < 4; ++r) {
            const int d = (j16 + mb + r - n) & (L_SZ - 1);
            atomicAdd(cb + d, acc[jj][r] * (1.0f / 64.0f));
        }
    }
}

// ---------------------------------------------------------------------------
// K3: per-(b,h) top-7 (tie -> lowest index) + softmax. One block per bh.
// ---------------------------------------------------------------------------
__global__ __launch_bounds__(256)
void topk_softmax(const float* __restrict__ corr, float* __restrict__ w,
                  int* __restrict__ delays) {
    __shared__ float cv[L_SZ];
    __shared__ float rv[256];
    __shared__ int   ri[256];
    __shared__ float topv[TOPK];
    __shared__ int   topi[TOPK];
    const int bh = blockIdx.x, tid = threadIdx.x;

    for (int i = tid; i < L_SZ; i += 256) cv[i] = corr[(size_t)bh * L_SZ + i];
    __syncthreads();

    for (int it = 0; it < TOPK; ++it) {
        float best = -INFINITY; int bi = 0;
        for (int i = tid; i < L_SZ; i += 256) {
            float x = cv[i];
            if (x > best) { best = x; bi = i; }
        }
        rv[tid] = best; ri[tid] = bi;
        __syncthreads();
        for (int stride = 128; stride > 0; stride >>= 1) {
            if (tid < stride) {
                float ov = rv[tid + stride]; int oi = ri[tid + stride];
                if (ov > rv[tid] || (ov == rv[tid] && oi < ri[tid])) {
                    rv[tid] = ov; ri[tid] = oi;
                }
            }
            __syncthreads();
        }
        if (tid == 0) {
            topv[it] = rv[0]; topi[it] = ri[0];
            cv[ri[0]] = -INFINITY;
        }
        __syncthreads();
    }

    if (tid == 0) {
        float mx = topv[0];
        float e[TOPK], s = 0.f;
#pragma unroll
        for (int i = 0; i < TOPK; ++i) { e[i] = expf(topv[i] - mx); s += e[i]; }
        const float inv = 1.0f / s;
#pragma unroll
        for (int i = 0; i < TOPK; ++i) {
            w[bh * TOPK + i] = e[i] * inv;
            delays[bh * TOPK + i] = topi[i];
        }
    }
}

// ---------------------------------------------------------------------------
// K4: mid[b,t,c] = sum_i w[bh,i] * V[b,(t - delay_i) % L, c]
// ---------------------------------------------------------------------------
__global__ __launch_bounds__(256)
void gather_combine(const float* __restrict__ V, const float* __restrict__ w,
                    const int* __restrict__ delays, float* __restrict__ mid) {
    const size_t g = (size_t)blockIdx.x * 256 + threadIdx.x;
    const int c4 = (int)(g & 255);
    const int t  = (int)((g >> 8) & (L_SZ - 1));
    const int b  = (int)(g >> 19);
    const int h  = c4 >> 4;
    const int bh = b * H_SZ + h;
    const size_t colbase = (size_t)b * L_SZ * D_SZ + (size_t)c4 * 4;

    float4 acc = {0.f, 0.f, 0.f, 0.f};
#pragma unroll
    for (int i = 0; i < TOPK; ++i) {
        const float wi = w[bh * TOPK + i];
        const int   di = delays[bh * TOPK + i];
        const int   ts = (t - di) & (L_SZ - 1);
        float4 v4 = *(const float4*)(V + colbase + (size_t)ts * D_SZ);
        acc.x += wi * v4.x; acc.y += wi * v4.y;
        acc.z += wi * v4.z; acc.w += wi * v4.w;
    }
    *(float4*)(mid + (size_t)b * L_SZ * D_SZ + (size_t)t * D_SZ + c4 * 4) = acc;
}

// ---------------------------------------------------------------------------
extern "C" void kernel_launch(void* const* d_in, const int* in_sizes, int n_in,
                              void* d_out, int out_size, void* d_ws, size_t ws_size,
                              hipStream_t stream) {
    const float* queries = (const float*)d_in[0];
    const float* keys    = (const float*)d_in[1];
    const float* values  = (const float*)d_in[2];
    const float* Wq = (const float*)d_in[3];
    const float* bq = (const float*)d_in[4];
    const float* Wk = (const float*)d_in[5];
    const float* bk = (const float*)d_in[6];
    const float* Wv = (const float*)d_in[7];
    const float* bv = (const float*)d_in[8];
    const float* Wo = (const float*)d_in[9];
    const float* bo = (const float*)d_in[10];

    const size_t NE = (size_t)M_SZ * D_SZ;          // 16.78M elements
    ushort_t* Qb16 = (ushort_t*)d_ws;               // 33.5 MB
    ushort_t* Kb16 = Qb16 + NE;                     // 33.5 MB
    float* Vb   = (float*)(Kb16 + NE);              // 67.1 MB
    float* corr = Vb + NE;                          // 1 MB (B*H*L fp32)
    float* wbuf = corr + (size_t)B_SZ * H_SZ * L_SZ;
    int*   dbuf = (int*)(wbuf + B_SZ * H_SZ * TOPK);
    ushort_t* WH = (ushort_t*)(dbuf + B_SZ * H_SZ * TOPK);  // 2 MB (reused)
    ushort_t* WL = WH + (size_t)D_SZ * D_SZ;                // 2 MB (reused)
    float* mid  = (float*)d_ws;  // aliases Qb16+Kb16 (67MB, dead after corr)

    dim3 ggemm(D_SZ / 128, M_SZ / 128);   // (8, 128)
    const int wn8 = D_SZ * D_SZ / 8;      // 131072

    split_fp32<<<(wn8 + 255) / 256, 256, 0, stream>>>(Wq, WH, WL, wn8);
    gemm_split_mfma<true><<<ggemm, 256, 0, stream>>>(queries, WH, WL, bq, Qb16, M_SZ, D_SZ, D_SZ);
    split_fp32<<<(wn8 + 255) / 256, 256, 0, stream>>>(Wk, WH, WL, wn8);
    gemm_split_mfma<true><<<ggemm, 256, 0, stream>>>(keys, WH, WL, bk, Kb16, M_SZ, D_SZ, D_SZ);
    split_fp32<<<(wn8 + 255) / 256, 256, 0, stream>>>(Wv, WH, WL, wn8);
    gemm_split_mfma<false><<<ggemm, 256, 0, stream>>>(values, WH, WL, bv, Vb, M_SZ, D_SZ, D_SZ);

    zero_f32<<<(B_SZ * H_SZ * L_SZ / 4 + 255) / 256, 256, 0, stream>>>(
        corr, B_SZ * H_SZ * L_SZ / 4);

    corr_mfma<<<dim3(B_SZ * H_SZ, 4), 256, 0, stream>>>(Qb16, Kb16, corr);

    topk_softmax<<<B_SZ * H_SZ, 256, 0, stream>>>(corr, wbuf, dbuf);

    gather_combine<<<(M_SZ * 256) / 256, 256, 0, stream>>>(Vb, wbuf, dbuf, mid);

    split_fp32<<<(wn8 + 255) / 256, 256, 0, stream>>>(Wo, WH, WL, wn8);
    gemm_split_mfma<false><<<ggemm, 256, 0, stream>>>(mid, WH, WL, bo, (float*)d_out, M_SZ, D_SZ, D_SZ);
}